// Round 3
// baseline (327.370 us; speedup 1.0000x reference)
//
#include <hip/hip_runtime.h>
#include <math.h>

constexpr int B = 2, S = 2048, E = 1024, H = 16, D = 64;
constexpr int M = B * S;  // 4096

typedef __attribute__((ext_vector_type(8))) short short8;
typedef __attribute__((ext_vector_type(4))) float f32x4;
#define MFMA_BF16 __builtin_amdgcn_mfma_f32_16x16x32_bf16

// Split fp32 into hi = bf16-truncate(x), lo = bf16-truncate(x - hi). Combined rel err ~2^-16.
__device__ __forceinline__ void split1(float f, short* h, short* l) {
  unsigned u = __float_as_uint(f);
  *h = (short)(u >> 16);
  float r = f - __uint_as_float(u & 0xFFFF0000u);
  *l = (short)(__float_as_uint(r) >> 16);
}

// Async global->LDS DMA, 16B per lane. LDS dest = wave-uniform base + lane*16.
__device__ __forceinline__ void gload16(const void* g, const void* l) {
  __builtin_amdgcn_global_load_lds(
      (const __attribute__((address_space(1))) unsigned*)g,
      (__attribute__((address_space(3))) unsigned*)l, 16, 0, 0);
}

struct GArgs {
  const short* Ah; const short* Al;   // A [Mrows x K] bf16 hi/lo, row-major
  const short* Bh; const short* Bl;   // B [N x K] bf16 hi/lo, row-major
  const float* bias;                  // EMIT=0 only
  void* C0; void* C1;                 // EMIT=0: C0=float out. EMIT=1: C0/C1 = bf16 hi/lo out
};

// C[m,n] = sum_k A[m,k]*B[n,k] via split-bf16 3-MFMA. BM in {64,128}, BN=128 fixed.
// 256 threads = 4 waves (2x2), each wave owns (BM/2)x64. K%32==0. blockIdx.z: batched GEMMs.
// LDS layout: Ah | Al | Bh | Bl tiles, each row = 32 bf16 (64B), chunk-swizzled:
//   chunk q of row r stored at slot (q + (r>>1)) & 3  -> conflict-free ds_read_b128.
template <int BM, int EMIT>
__global__ __launch_bounds__(256, 2) void gemm3s(GArgs g0, GArgs g1, GArgs g2, int K, int N) {
  const GArgs g = (blockIdx.z == 0) ? g0 : (blockIdx.z == 1 ? g1 : g2);
  constexpr int SA = BM / 16;        // 1KB staging segments per A tile
  constexpr int TOT = 2 * SA + 16;   // total staging instructions per iter
  constexpr int PW = TOT / 4;        // per wave
  constexpr int MT = BM / 32;        // 16-row m-tiles per wave
  __shared__ short lds[TOT * 512];

  const int tid = threadIdx.x, wave = tid >> 6, lane = tid & 63;
  const int bm = blockIdx.x * BM, bn = blockIdx.y * 128;

  // --- staging addresses: instruction n = wave*PW+j covers 16 rows of one tile ---
  const short* gb[PW];
#pragma unroll
  for (int j = 0; j < PW; ++j) {
    const int n = wave * PW + j;
    const short* src; int seg, rowbase;
    if (n < SA)              { src = g.Ah; seg = n;            rowbase = bm; }
    else if (n < 2 * SA)     { src = g.Al; seg = n - SA;       rowbase = bm; }
    else if (n < 2 * SA + 8) { src = g.Bh; seg = n - 2 * SA;   rowbase = bn; }
    else                     { src = g.Bl; seg = n - 2 * SA - 8; rowbase = bn; }
    const int r = seg * 16 + (lane >> 2);   // row within tile
    const int p = lane & 3;                 // LDS slot this lane fills
    const int q = (p - ((r >> 1) & 3)) & 3; // global k-chunk that belongs in slot p
    gb[j] = src + (size_t)(rowbase + r) * K + q * 8;
  }

  // --- fragment read offsets (constant; LDS is re-staged in place each iter) ---
  const int fr = lane & 15, fq = lane >> 4;
  const int wm = (wave & 1) * (BM / 2), wn = (wave >> 1) * 64;
  int aoh[MT], aol[MT], boh[4], bol[4];
#pragma unroll
  for (int mi = 0; mi < MT; ++mi) {
    const int r = wm + mi * 16 + fr;
    const int slot = (fq + ((r >> 1) & 3)) & 3;
    aoh[mi] = r * 32 + slot * 8;
    aol[mi] = BM * 32 + aoh[mi];
  }
#pragma unroll
  for (int ni = 0; ni < 4; ++ni) {
    const int r = wn + ni * 16 + fr;
    const int slot = (fq + ((r >> 1) & 3)) & 3;
    boh[ni] = 2 * BM * 32 + r * 32 + slot * 8;
    bol[ni] = boh[ni] + 4096;
  }

  f32x4 acc[MT][4] = {};
  const int ldsW = wave * PW * 512;

  for (int k0 = 0; k0 < K; k0 += 32) {
#pragma unroll
    for (int j = 0; j < PW; ++j)
      gload16(gb[j] + k0, &lds[ldsW + j * 512]);
    __syncthreads();  // compiler drains vmcnt(0) before s_barrier
    short8 ah[MT], al[MT], bh[4], bl[4];
#pragma unroll
    for (int mi = 0; mi < MT; ++mi) {
      ah[mi] = *(const short8*)&lds[aoh[mi]];
      al[mi] = *(const short8*)&lds[aol[mi]];
    }
#pragma unroll
    for (int ni = 0; ni < 4; ++ni) {
      bh[ni] = *(const short8*)&lds[boh[ni]];
      bl[ni] = *(const short8*)&lds[bol[ni]];
    }
#pragma unroll
    for (int mi = 0; mi < MT; ++mi)
#pragma unroll
      for (int ni = 0; ni < 4; ++ni) {
        acc[mi][ni] = MFMA_BF16(ah[mi], bh[ni], acc[mi][ni], 0, 0, 0);
        acc[mi][ni] = MFMA_BF16(ah[mi], bl[ni], acc[mi][ni], 0, 0, 0);
        acc[mi][ni] = MFMA_BF16(al[mi], bh[ni], acc[mi][ni], 0, 0, 0);
      }
    __syncthreads();
  }

  // --- epilogue: C/D layout col=lane&15, row=(lane>>4)*4+reg (m89-verified) ---
  if (EMIT == 0) {
    float* C = (float*)g.C0;
#pragma unroll
    for (int ni = 0; ni < 4; ++ni) {
      const int n = bn + wn + ni * 16 + fr;
      const float bv = g.bias[n];
#pragma unroll
      for (int mi = 0; mi < MT; ++mi) {
        const int m0 = bm + wm + mi * 16 + fq * 4;
#pragma unroll
        for (int r2 = 0; r2 < 4; ++r2)
          C[(size_t)(m0 + r2) * N + n] = acc[mi][ni][r2] + bv;
      }
    }
  } else {
    short* Ch = (short*)g.C0;
    short* Cl = (short*)g.C1;
#pragma unroll
    for (int ni = 0; ni < 4; ++ni) {
      const int n = bn + wn + ni * 16 + fr;
#pragma unroll
      for (int mi = 0; mi < MT; ++mi) {
        const int m0 = bm + wm + mi * 16 + fq * 4;
#pragma unroll
        for (int r2 = 0; r2 < 4; ++r2) {
          short h, l;
          split1(acc[mi][ni][r2], &h, &l);
          Ch[(size_t)(m0 + r2) * N + n] = h;
          Cl[(size_t)(m0 + r2) * N + n] = l;
        }
      }
    }
  }
}

// Grid-stride split of up to 4 fp32 arrays into bf16 hi/lo pairs (z selects).
__global__ __launch_bounds__(256) void split4(
    const float* s0, short* h0, short* l0, int n0,
    const float* s1, short* h1, short* l1, int n1,
    const float* s2, short* h2, short* l2, int n2,
    const float* s3, short* h3, short* l3, int n3) {
  const float* s; short* h; short* l; int n;
  switch (blockIdx.z) {
    case 0: s = s0; h = h0; l = l0; n = n0; break;
    case 1: s = s1; h = h1; l = l1; n = n1; break;
    case 2: s = s2; h = h2; l = l2; n = n2; break;
    default: s = s3; h = h3; l = l3; n = n3; break;
  }
  const int stride = gridDim.x * blockDim.x;
  for (int i = blockIdx.x * blockDim.x + threadIdx.x; i < n / 4; i += stride) {
    float4 v = ((const float4*)s)[i];
    short4 hh, ll;
    split1(v.x, &hh.x, &ll.x);
    split1(v.y, &hh.y, &ll.y);
    split1(v.z, &hh.z, &ll.z);
    split1(v.w, &hh.w, &ll.w);
    ((short4*)h)[i] = hh;
    ((short4*)l)[i] = ll;
  }
}

// Transpose two ExE fp32 matrices, emitting split bf16 hi/lo.
__global__ __launch_bounds__(256) void transpose_split2(
    const float* i0, short* h0, short* l0,
    const float* i1, short* h1, short* l1) {
  const float* in = blockIdx.z ? i1 : i0;
  short* oh = blockIdx.z ? h1 : h0;
  short* ol = blockIdx.z ? l1 : l0;
  __shared__ float t[32][33];
  const int x = threadIdx.x & 31, y0 = threadIdx.x >> 5;
  const int bx = blockIdx.x * 32, by = blockIdx.y * 32;
#pragma unroll
  for (int i = 0; i < 32; i += 8) t[y0 + i][x] = in[(size_t)(by + y0 + i) * E + bx + x];
  __syncthreads();
#pragma unroll
  for (int i = 0; i < 32; i += 8) {
    short h, l;
    split1(t[x][y0 + i], &h, &l);
    const size_t o = (size_t)(bx + y0 + i) * E + by + x;
    oh[o] = h;
    ol[o] = l;
  }
}

// o[n] = dot(Wf[n,:], bin) + bf[n]; one wave per n; blockIdx.y selects set.
__global__ __launch_bounds__(256) void bias_combine2(
    const float* __restrict__ Wf0, const float* __restrict__ b0, const float* __restrict__ bf0, float* __restrict__ o0,
    const float* __restrict__ Wf1, const float* __restrict__ b1, const float* __restrict__ bf1, float* __restrict__ o1) {
  const float* Wf = blockIdx.y ? Wf1 : Wf0;
  const float* bin = blockIdx.y ? b1 : b0;
  const float* bf = blockIdx.y ? bf1 : bf0;
  float* o = blockIdx.y ? o1 : o0;
  const int lane = threadIdx.x & 63;
  const int n = blockIdx.x * 4 + (threadIdx.x >> 6);
  float s = 0.f;
  for (int j = lane; j < E; j += 64) s += Wf[(size_t)n * E + j] * bin[j];
#pragma unroll
  for (int off = 32; off; off >>= 1) s += __shfl_xor(s, off, 64);
  if (lane == 0) o[n] = s + bf[n];
}

// In-place row softmax over E columns; blockIdx.y selects buffer.
__global__ __launch_bounds__(256) void softmax2(float* __restrict__ X0, float* __restrict__ X1) {
  float* X = blockIdx.y ? X1 : X0;
  float* x = X + (size_t)blockIdx.x * E;
  const int tid = threadIdx.x;
  float v[4];
  float mx = -3.4e38f;
#pragma unroll
  for (int i = 0; i < 4; ++i) {
    v[i] = x[tid + i * 256];
    mx = fmaxf(mx, v[i]);
  }
#pragma unroll
  for (int off = 32; off; off >>= 1) mx = fmaxf(mx, __shfl_xor(mx, off, 64));
  __shared__ float redm[4], reds[4];
  if ((tid & 63) == 0) redm[tid >> 6] = mx;
  __syncthreads();
  mx = fmaxf(fmaxf(redm[0], redm[1]), fmaxf(redm[2], redm[3]));
  float s = 0.f;
#pragma unroll
  for (int i = 0; i < 4; ++i) {
    v[i] = expf(v[i] - mx);
    s += v[i];
  }
#pragma unroll
  for (int off = 32; off; off >>= 1) s += __shfl_xor(s, off, 64);
  if ((tid & 63) == 0) reds[tid >> 6] = s;
  __syncthreads();
  s = reds[0] + reds[1] + reds[2] + reds[3];
  const float inv = 1.0f / s;
#pragma unroll
  for (int i = 0; i < 4; ++i) x[tid + i * 256] = v[i] * inv;
}

// KV[bh][d][d'] += sum_t k[t]*v[t]; ksum[bh][d] += sum_t k[t]  (fp32, atomics into zeroed ws)
__global__ __launch_bounds__(256) void kv_kernel(const float* __restrict__ kf,
                                                 const float* __restrict__ v,
                                                 float* __restrict__ KV,
                                                 float* __restrict__ ksum) {
  const int bh = blockIdx.x;
  const int b = bh / H, h = bh % H;
  const int t0 = blockIdx.y * 128;
  const float* kbase = kf + (size_t)b * S * E + (size_t)h * D;
  const float* vbase = v + (size_t)b * S * E + (size_t)h * D;
  __shared__ float ks[16][D];
  __shared__ float vs[16][D];
  const int tid = threadIdx.x;
  const int a4 = tid & 15, b4 = tid >> 4;
  float acc[4][4] = {};
  float ksm[4] = {};
  for (int ts = 0; ts < 128; ts += 16) {
#pragma unroll
    for (int i = 0; i < 4; ++i) {
      const int idx = tid + i * 256;
      const int tt = idx >> 6, d = idx & 63;
      const size_t roff = (size_t)(t0 + ts + tt) * E + d;
      ks[tt][d] = kbase[roff];
      vs[tt][d] = vbase[roff];
    }
    __syncthreads();
#pragma unroll
    for (int tt = 0; tt < 16; ++tt) {
      float kk4[4], vv4[4];
#pragma unroll
      for (int i = 0; i < 4; ++i) kk4[i] = ks[tt][a4 * 4 + i];
#pragma unroll
      for (int j = 0; j < 4; ++j) vv4[j] = vs[tt][b4 * 4 + j];
#pragma unroll
      for (int i = 0; i < 4; ++i) {
        ksm[i] += kk4[i];
#pragma unroll
        for (int j = 0; j < 4; ++j) acc[i][j] = fmaf(kk4[i], vv4[j], acc[i][j]);
      }
    }
    __syncthreads();
  }
#pragma unroll
  for (int i = 0; i < 4; ++i)
#pragma unroll
    for (int j = 0; j < 4; ++j)
      atomicAdd(&KV[((size_t)bh * D + a4 * 4 + i) * D + b4 * 4 + j], acc[i][j]);
  if (b4 == 0) {
#pragma unroll
    for (int i = 0; i < 4; ++i) atomicAdd(&ksum[bh * D + a4 * 4 + i], ksm[i]);
  }
}

// Output: block per (bh, 256-row chunk). KV[bh] staged in LDS once.
__global__ __launch_bounds__(256) void out_v2(const float* __restrict__ qf,
                                              const float* __restrict__ KV,
                                              const float* __restrict__ ksum,
                                              float* __restrict__ out) {
  const int bh = blockIdx.x;
  const int b = bh >> 4, h = bh & 15;
  __shared__ float KVs[64][65];
  __shared__ float kss[64];
  __shared__ float qs[4][64];
  const int tid = threadIdx.x;
  for (int i = tid; i < 4096; i += 256) KVs[i >> 6][i & 63] = KV[(size_t)bh * 4096 + i];
  if (tid < 64) kss[tid] = ksum[bh * 64 + tid];
  __syncthreads();
  const int wave = tid >> 6, lane = tid & 63;
  const int r0 = blockIdx.y * 256;
  for (int rr = r0 + wave; rr < r0 + 256; rr += 4) {
    const size_t rowoff = ((size_t)b * S + rr) * E + h * 64;
    const float qd = qf[rowoff + lane];
    float dn = qd * kss[lane];
#pragma unroll
    for (int off = 32; off; off >>= 1) dn += __shfl_xor(dn, off, 64);
    qs[wave][lane] = qd;
    float num = 0.f;
#pragma unroll 16
    for (int d = 0; d < 64; ++d) num = fmaf(qs[wave][d], KVs[d][lane], num);
    out[rowoff + lane] = num / dn;
  }
}

extern "C" void kernel_launch(void* const* d_in, const int* in_sizes, int n_in,
                              void* d_out, int out_size, void* d_ws, size_t ws_size,
                              hipStream_t stream) {
  const float* hs = (const float*)d_in[0];
  const float* Wq = (const float*)d_in[1];
  const float* bq = (const float*)d_in[2];
  const float* Wk = (const float*)d_in[3];
  const float* bk = (const float*)d_in[4];
  const float* Wv = (const float*)d_in[5];
  const float* bv = (const float*)d_in[6];
  const float* Wfq = (const float*)d_in[7];
  const float* bfq = (const float*)d_in[8];
  const float* Wfk = (const float*)d_in[9];
  const float* bfk = (const float*)d_in[10];
  float* out = (float*)d_out;

  const size_t MEG = 1024 * 1024;
  float* ws = (float*)d_ws;
  // big fp32 buffers
  float* qf = ws;                         // [M,E] 16 MB
  float* kf = ws + 4 * MEG;               // [M,E] 16 MB
  float* vreg = ws + 8 * MEG;             // [M,E] 16 MB (written LAST among GEMMs)
  // early split scratch aliased inside vreg (dead before vreg is written):
  short* sb = (short*)vreg;
  short* WqT_h = sb + 0 * MEG; short* WqT_l = sb + 1 * MEG;
  short* WkT_h = sb + 2 * MEG; short* WkT_l = sb + 3 * MEG;
  short* Wfq_h = sb + 4 * MEG; short* Wfq_l = sb + 5 * MEG;
  short* Wfk_h = sb + 6 * MEG; short* Wfk_l = sb + 7 * MEG;
  // persistent split buffers
  short* hs_h = (short*)(ws + 12 * MEG);  // 4M bf16
  short* hs_l = hs_h + 4 * MEG;           // 4M bf16  (ends at ws+16M floats)
  short* Wv_h = (short*)(ws + 16 * MEG); short* Wv_l = Wv_h + MEG;
  short* WcQ_h = (short*)(ws + 17 * MEG); short* WcQ_l = WcQ_h + MEG;
  short* WcK_h = (short*)(ws + 18 * MEG); short* WcK_l = WcK_h + MEG;
  float* bcQ = ws + 19 * MEG;
  float* bcK = bcQ + 1024;
  float* KV = bcK + 1024;                 // [32,64,64]
  float* ksum = KV + 32 * 4096;           // [32,64]

  // 1) Split Wfq, Wfk, Wv, hs into bf16 hi/lo.
  split4<<<dim3(1024, 1, 4), 256, 0, stream>>>(
      Wfq, Wfq_h, Wfq_l, (int)MEG,
      Wfk, Wfk_h, Wfk_l, (int)MEG,
      Wv, Wv_h, Wv_l, (int)MEG,
      hs, hs_h, hs_l, (int)(4 * MEG));
  // 2) Transpose+split Wq, Wk.
  transpose_split2<<<dim3(32, 32, 2), 256, 0, stream>>>(Wq, WqT_h, WqT_l, Wk, WkT_h, WkT_l);
  // 3) Combined biases bc = Wf @ b + bf (exact fp32).
  bias_combine2<<<dim3(256, 2), 256, 0, stream>>>(Wfq, bq, bfq, bcQ, Wfk, bk, bfk, bcK);
  // 4) Combined weights Wc = Wf @ W, emitted pre-split. [1024,1024,K=1024] x2.
  GArgs sw0 = {Wfq_h, Wfq_l, WqT_h, WqT_l, nullptr, (void*)WcQ_h, (void*)WcQ_l};
  GArgs sw1 = {Wfk_h, Wfk_l, WkT_h, WkT_l, nullptr, (void*)WcK_h, (void*)WcK_l};
  gemm3s<64, 1><<<dim3(16, 8, 2), 256, 0, stream>>>(sw0, sw1, sw1, E, E);
  // 5) Fused big GEMM (z=3): q-logits, k-logits, v. [4096,1024,K=1024] each.
  GArgs bg0 = {hs_h, hs_l, WcQ_h, WcQ_l, bcQ, (void*)qf, nullptr};
  GArgs bg1 = {hs_h, hs_l, WcK_h, WcK_l, bcK, (void*)kf, nullptr};
  GArgs bg2 = {hs_h, hs_l, Wv_h, Wv_l, bv, (void*)vreg, nullptr};
  gemm3s<128, 0><<<dim3(32, 8, 3), 256, 0, stream>>>(bg0, bg1, bg2, E, E);
  // 6) Row softmax (q and k).
  softmax2<<<dim3(M, 2), 256, 0, stream>>>(qf, kf);
  // 7) KV accumulation + output.
  hipMemsetAsync(KV, 0, (size_t)(32 * 4096 + 32 * 64) * sizeof(float), stream);
  kv_kernel<<<dim3(B * H, S / 128), 256, 0, stream>>>(kf, vreg, KV, ksum);
  out_v2<<<dim3(B * H, S / 256), 256, 0, stream>>>(qf, KV, ksum, out);
}

// Round 4
// 294.012 us; speedup vs baseline: 1.1135x; 1.1135x over previous
//
#include <hip/hip_runtime.h>
#include <math.h>

constexpr int B = 2, S = 2048, E = 1024, H = 16, D = 64;
constexpr int M = B * S;  // 4096

typedef __attribute__((ext_vector_type(8))) short short8;
typedef __attribute__((ext_vector_type(4))) float f32x4;
#define MFMA_BF16 __builtin_amdgcn_mfma_f32_16x16x32_bf16
// wait until at most N vector-memory ops outstanding; leave lgkm/exp unconstrained
#define WAITCNT_VM(N) __builtin_amdgcn_s_waitcnt(0xF70 | (N))

// Split fp32 into hi = bf16-truncate(x), lo = bf16-truncate(x - hi). Combined rel err ~2^-16.
__device__ __forceinline__ void split1(float f, short* h, short* l) {
  unsigned u = __float_as_uint(f);
  *h = (short)(u >> 16);
  float r = f - __uint_as_float(u & 0xFFFF0000u);
  *l = (short)(__float_as_uint(r) >> 16);
}

// Async global->LDS DMA, 16B per lane. LDS dest = wave-uniform base + lane*16.
__device__ __forceinline__ void gload16(const void* g, const void* l) {
  __builtin_amdgcn_global_load_lds(
      (const __attribute__((address_space(1))) unsigned*)g,
      (__attribute__((address_space(3))) unsigned*)l, 16, 0, 0);
}

struct GArgs {
  const short* Ah; const short* Al;   // A [Mrows x K] bf16 hi/lo, row-major
  const short* Bh; const short* Bl;   // B [N x K] bf16 hi/lo, row-major
  const float* bias;                  // EMIT=0 only
  void* C0; void* C1;                 // EMIT=0: C0=float out. EMIT=1: C0/C1 = bf16 hi/lo out
};

// C[m,n] = sum_k A[m,k]*B[n,k] via split-bf16 3-MFMA. BM in {64,128}, BN=128 fixed.
// 256 threads = 4 waves (2x2), each wave owns (BM/2)x64. K%32==0, K>=128. z: batched GEMMs.
// Pipelined K-loop: double-buffered LDS, raw s_barrier, s_waitcnt vmcnt(PW) (never 0
// mid-loop) so the 2-ahead prefetch stays in flight across barriers (AITER-style).
template <int BM, int EMIT>
__global__ __launch_bounds__(256, 2) void gemm3s(GArgs g0, GArgs g1, GArgs g2, int K, int N) {
  const GArgs g = (blockIdx.z == 0) ? g0 : (blockIdx.z == 1 ? g1 : g2);
  constexpr int SA = BM / 16;        // 1KB staging segments per A tile
  constexpr int TOT = 2 * SA + 16;   // total staging instructions per iter
  constexpr int PW = TOT / 4;        // per wave
  constexpr int MT = BM / 32;        // 16-row m-tiles per wave
  __shared__ short lds[2][TOT * 512];

  const int tid = threadIdx.x, wave = tid >> 6, lane = tid & 63;
  const int bm = blockIdx.x * BM, bn = blockIdx.y * 128;

  // --- staging addresses: instruction n = wave*PW+j covers 16 rows of one tile ---
  const short* gb[PW];
#pragma unroll
  for (int j = 0; j < PW; ++j) {
    const int n = wave * PW + j;
    const short* src; int seg, rowbase;
    if (n < SA)              { src = g.Ah; seg = n;            rowbase = bm; }
    else if (n < 2 * SA)     { src = g.Al; seg = n - SA;       rowbase = bm; }
    else if (n < 2 * SA + 8) { src = g.Bh; seg = n - 2 * SA;   rowbase = bn; }
    else                     { src = g.Bl; seg = n - 2 * SA - 8; rowbase = bn; }
    const int r = seg * 16 + (lane >> 2);   // row within tile
    const int p = lane & 3;                 // LDS slot this lane fills
    const int q = (p - ((r >> 1) & 3)) & 3; // global k-chunk that belongs in slot p
    gb[j] = src + (size_t)(rowbase + r) * K + q * 8;
  }

  // --- fragment read offsets (swizzled chunk layout -> conflict-free ds_read_b128) ---
  const int fr = lane & 15, fq = lane >> 4;
  const int wm = (wave & 1) * (BM / 2), wn = (wave >> 1) * 64;
  int aoh[MT], aol[MT], boh[4], bol[4];
#pragma unroll
  for (int mi = 0; mi < MT; ++mi) {
    const int r = wm + mi * 16 + fr;
    const int slot = (fq + ((r >> 1) & 3)) & 3;
    aoh[mi] = r * 32 + slot * 8;
    aol[mi] = BM * 32 + aoh[mi];
  }
#pragma unroll
  for (int ni = 0; ni < 4; ++ni) {
    const int r = wn + ni * 16 + fr;
    const int slot = (fq + ((r >> 1) & 3)) & 3;
    boh[ni] = 2 * BM * 32 + r * 32 + slot * 8;
    bol[ni] = boh[ni] + 4096;
  }

  f32x4 acc[MT][4] = {};
  const int ldsW = wave * PW * 512;

  auto stageAll = [&](int buf, int k0) {
#pragma unroll
    for (int j = 0; j < PW; ++j)
      gload16(gb[j] + k0, &lds[buf][ldsW + j * 512]);
  };

  stageAll(0, 0);
  stageAll(1, 32);
  int buf = 0;
  for (int k0 = 0; k0 < K; k0 += 32) {
    // wait for the current buffer's DMA batch (oldest); later batch may stay in flight
    if (k0 + 32 < K) WAITCNT_VM(PW); else WAITCNT_VM(0);
    __builtin_amdgcn_s_barrier();
    short8 ah[MT], al[MT], bh4[4], bl4[4];
#pragma unroll
    for (int mi = 0; mi < MT; ++mi) {
      ah[mi] = *(const short8*)&lds[buf][aoh[mi]];
      al[mi] = *(const short8*)&lds[buf][aol[mi]];
    }
#pragma unroll
    for (int ni = 0; ni < 4; ++ni) {
      bh4[ni] = *(const short8*)&lds[buf][boh[ni]];
      bl4[ni] = *(const short8*)&lds[buf][bol[ni]];
    }
#pragma unroll
    for (int mi = 0; mi < MT; ++mi)
#pragma unroll
      for (int ni = 0; ni < 4; ++ni) {
        acc[mi][ni] = MFMA_BF16(ah[mi], bh4[ni], acc[mi][ni], 0, 0, 0);
        acc[mi][ni] = MFMA_BF16(ah[mi], bl4[ni], acc[mi][ni], 0, 0, 0);
        acc[mi][ni] = MFMA_BF16(al[mi], bh4[ni], acc[mi][ni], 0, 0, 0);
      }
    __builtin_amdgcn_s_barrier();  // all waves done reading lds[buf]
    if (k0 + 64 < K) stageAll(buf, k0 + 64);
    buf ^= 1;
  }

  // --- epilogue: C/D layout col=lane&15, row=(lane>>4)*4+reg (m89-verified) ---
  if (EMIT == 0) {
    float* C = (float*)g.C0;
#pragma unroll
    for (int ni = 0; ni < 4; ++ni) {
      const int n = bn + wn + ni * 16 + fr;
      const float bv = g.bias[n];
#pragma unroll
      for (int mi = 0; mi < MT; ++mi) {
        const int m0 = bm + wm + mi * 16 + fq * 4;
#pragma unroll
        for (int r2 = 0; r2 < 4; ++r2)
          C[(size_t)(m0 + r2) * N + n] = acc[mi][ni][r2] + bv;
      }
    }
  } else {
    short* Ch = (short*)g.C0;
    short* Cl = (short*)g.C1;
#pragma unroll
    for (int ni = 0; ni < 4; ++ni) {
      const int n = bn + wn + ni * 16 + fr;
#pragma unroll
      for (int mi = 0; mi < MT; ++mi) {
        const int m0 = bm + wm + mi * 16 + fq * 4;
#pragma unroll
        for (int r2 = 0; r2 < 4; ++r2) {
          short h, l;
          split1(acc[mi][ni][r2], &h, &l);
          Ch[(size_t)(m0 + r2) * N + n] = h;
          Cl[(size_t)(m0 + r2) * N + n] = l;
        }
      }
    }
  }
}

// One fused prep dispatch (4352 blocks):
//   [0,1792)    split {Wfq,Wfk,Wv,hs} fp32 -> bf16 hi/lo
//   [1792,3840) transpose+split {Wq,Wk}
//   [3840,4352) bias combine bc = Wf @ b + bf (fp32)
__global__ __launch_bounds__(256) void prep(
    const float* __restrict__ Wfq, short* Wfq_h, short* Wfq_l,
    const float* __restrict__ Wfk, short* Wfk_h, short* Wfk_l,
    const float* __restrict__ Wv, short* Wv_h, short* Wv_l,
    const float* __restrict__ hs, short* hs_h, short* hs_l,
    const float* __restrict__ Wq, short* WqT_h, short* WqT_l,
    const float* __restrict__ Wk, short* WkT_h, short* WkT_l,
    const float* __restrict__ bq, const float* __restrict__ bfq, float* bcQ,
    const float* __restrict__ bk, const float* __restrict__ bfk, float* bcK) {
  __shared__ float tb[32][33];
  const int blk = blockIdx.x, tid = threadIdx.x;
  if (blk < 1792) {
    const float* s; short* h; short* l; int base;
    if (blk < 256)      { s = Wfq; h = Wfq_h; l = Wfq_l; base = blk; }
    else if (blk < 512) { s = Wfk; h = Wfk_h; l = Wfk_l; base = blk - 256; }
    else if (blk < 768) { s = Wv;  h = Wv_h;  l = Wv_l;  base = blk - 512; }
    else                { s = hs;  h = hs_h;  l = hs_l;  base = blk - 768; }
#pragma unroll
    for (int p = 0; p < 4; ++p) {
      const int i = base * 1024 + p * 256 + tid;  // float4 index
      float4 v = ((const float4*)s)[i];
      short4 hh, ll;
      split1(v.x, &hh.x, &ll.x); split1(v.y, &hh.y, &ll.y);
      split1(v.z, &hh.z, &ll.z); split1(v.w, &hh.w, &ll.w);
      ((short4*)h)[i] = hh; ((short4*)l)[i] = ll;
    }
  } else if (blk < 3840) {
    const int t = blk - 1792;
    const float* in = (t < 1024) ? Wq : Wk;
    short* oh = (t < 1024) ? WqT_h : WkT_h;
    short* ol = (t < 1024) ? WqT_l : WkT_l;
    const int tt = t & 1023;
    const int bx = (tt & 31) * 32, by = (tt >> 5) * 32;
    const int x = tid & 31, y0 = tid >> 5;
#pragma unroll
    for (int i = 0; i < 32; i += 8) tb[y0 + i][x] = in[(size_t)(by + y0 + i) * E + bx + x];
    __syncthreads();
#pragma unroll
    for (int i = 0; i < 32; i += 8) {
      short h2, l2;
      split1(tb[x][y0 + i], &h2, &l2);
      const size_t o = (size_t)(bx + y0 + i) * E + by + x;
      oh[o] = h2; ol[o] = l2;
    }
  } else {
    const int t = blk - 3840;
    const float* Wf = (t < 256) ? Wfq : Wfk;
    const float* bin = (t < 256) ? bq : bk;
    const float* bf = (t < 256) ? bfq : bfk;
    float* o = (t < 256) ? bcQ : bcK;
    const int n = (t & 255) * 4 + (tid >> 6);
    const int lane = tid & 63;
    float sacc = 0.f;
    for (int j = lane; j < E; j += 64) sacc += Wf[(size_t)n * E + j] * bin[j];
#pragma unroll
    for (int off = 32; off; off >>= 1) sacc += __shfl_xor(sacc, off, 64);
    if (lane == 0) o[n] = sacc + bf[n];
  }
}

// In-place row softmax over E columns; blockIdx.y selects buffer.
__global__ __launch_bounds__(256) void softmax2(float* __restrict__ X0, float* __restrict__ X1) {
  float* X = blockIdx.y ? X1 : X0;
  float* x = X + (size_t)blockIdx.x * E;
  const int tid = threadIdx.x;
  float v[4];
  float mx = -3.4e38f;
#pragma unroll
  for (int i = 0; i < 4; ++i) {
    v[i] = x[tid + i * 256];
    mx = fmaxf(mx, v[i]);
  }
#pragma unroll
  for (int off = 32; off; off >>= 1) mx = fmaxf(mx, __shfl_xor(mx, off, 64));
  __shared__ float redm[4], reds[4];
  if ((tid & 63) == 0) redm[tid >> 6] = mx;
  __syncthreads();
  mx = fmaxf(fmaxf(redm[0], redm[1]), fmaxf(redm[2], redm[3]));
  float s = 0.f;
#pragma unroll
  for (int i = 0; i < 4; ++i) {
    v[i] = expf(v[i] - mx);
    s += v[i];
  }
#pragma unroll
  for (int off = 32; off; off >>= 1) s += __shfl_xor(s, off, 64);
  if ((tid & 63) == 0) reds[tid >> 6] = s;
  __syncthreads();
  s = reds[0] + reds[1] + reds[2] + reds[3];
  const float inv = 1.0f / s;
#pragma unroll
  for (int i = 0; i < 4; ++i) x[tid + i * 256] = v[i] * inv;
}

// Per-chunk KV partials (no atomics, no memset): block (bh, chunk of 128 t).
// KVp[(bh*16+chunk)][64][64], ksump[(bh*16+chunk)][64].
__global__ __launch_bounds__(256) void kv_part(const float* __restrict__ kf,
                                               const float* __restrict__ v,
                                               float* __restrict__ KVp,
                                               float* __restrict__ ksump) {
  const int bh = blockIdx.x;
  const int b = bh / H, h = bh % H;
  const int t0 = blockIdx.y * 128;
  const float* kbase = kf + (size_t)b * S * E + (size_t)h * D;
  const float* vbase = v + (size_t)b * S * E + (size_t)h * D;
  __shared__ float ks[16][D];
  __shared__ float vs[16][D];
  const int tid = threadIdx.x;
  const int a4 = tid & 15, b4 = tid >> 4;
  float acc[4][4] = {};
  float ksm[4] = {};
  for (int ts = 0; ts < 128; ts += 16) {
#pragma unroll
    for (int i = 0; i < 4; ++i) {
      const int idx = tid + i * 256;
      const int tt = idx >> 6, d = idx & 63;
      const size_t roff = (size_t)(t0 + ts + tt) * E + d;
      ks[tt][d] = kbase[roff];
      vs[tt][d] = vbase[roff];
    }
    __syncthreads();
#pragma unroll
    for (int tt = 0; tt < 16; ++tt) {
      float kk4[4], vv4[4];
#pragma unroll
      for (int i = 0; i < 4; ++i) kk4[i] = ks[tt][a4 * 4 + i];
#pragma unroll
      for (int j = 0; j < 4; ++j) vv4[j] = vs[tt][b4 * 4 + j];
#pragma unroll
      for (int i = 0; i < 4; ++i) {
        ksm[i] += kk4[i];
#pragma unroll
        for (int j = 0; j < 4; ++j) acc[i][j] = fmaf(kk4[i], vv4[j], acc[i][j]);
      }
    }
    __syncthreads();
  }
  float* kvout = KVp + ((size_t)bh * 16 + blockIdx.y) * 4096;
#pragma unroll
  for (int i = 0; i < 4; ++i)
#pragma unroll
    for (int j = 0; j < 4; ++j)
      kvout[(a4 * 4 + i) * 64 + b4 * 4 + j] = acc[i][j];
  if (b4 == 0) {
    float* kso = ksump + ((size_t)bh * 16 + blockIdx.y) * 64;
#pragma unroll
    for (int i = 0; i < 4; ++i) kso[a4 * 4 + i] = ksm[i];
  }
}

// Output: block per (bh, 256-row chunk). Reduces the 16 KV partials into LDS once.
__global__ __launch_bounds__(256) void out_v3(const float* __restrict__ qf,
                                              const float* __restrict__ KVp,
                                              const float* __restrict__ ksump,
                                              float* __restrict__ out) {
  const int bh = blockIdx.x;
  const int b = bh >> 4, h = bh & 15;
  __shared__ float KVs[64][65];
  __shared__ float kss[64];
  __shared__ float qs[4][64];
  const int tid = threadIdx.x;
  for (int i = tid; i < 4096; i += 256) {
    float s = 0.f;
#pragma unroll
    for (int c = 0; c < 16; ++c) s += KVp[((size_t)bh * 16 + c) * 4096 + i];
    KVs[i >> 6][i & 63] = s;
  }
  if (tid < 64) {
    float s = 0.f;
#pragma unroll
    for (int c = 0; c < 16; ++c) s += ksump[((size_t)bh * 16 + c) * 64 + tid];
    kss[tid] = s;
  }
  __syncthreads();
  const int wave = tid >> 6, lane = tid & 63;
  const int r0 = blockIdx.y * 256;
  for (int rr = r0 + wave; rr < r0 + 256; rr += 4) {
    const size_t rowoff = ((size_t)b * S + rr) * E + h * 64;
    const float qd = qf[rowoff + lane];
    float dn = qd * kss[lane];
#pragma unroll
    for (int off = 32; off; off >>= 1) dn += __shfl_xor(dn, off, 64);
    qs[wave][lane] = qd;
    float num = 0.f;
#pragma unroll 16
    for (int d = 0; d < 64; ++d) num = fmaf(qs[wave][d], KVs[d][lane], num);
    out[rowoff + lane] = num / dn;
  }
}

extern "C" void kernel_launch(void* const* d_in, const int* in_sizes, int n_in,
                              void* d_out, int out_size, void* d_ws, size_t ws_size,
                              hipStream_t stream) {
  const float* hs = (const float*)d_in[0];
  const float* Wq = (const float*)d_in[1];
  const float* bq = (const float*)d_in[2];
  const float* Wk = (const float*)d_in[3];
  const float* bk = (const float*)d_in[4];
  const float* Wv = (const float*)d_in[5];
  const float* bv = (const float*)d_in[6];
  const float* Wfq = (const float*)d_in[7];
  const float* bfq = (const float*)d_in[8];
  const float* Wfk = (const float*)d_in[9];
  const float* bfk = (const float*)d_in[10];
  float* out = (float*)d_out;

  const size_t MEG = 1024 * 1024;
  float* ws = (float*)d_ws;
  float* qf = ws;                         // [M,E] 16 MB
  float* kf = ws + 4 * MEG;               // [M,E] 16 MB
  float* vreg = ws + 8 * MEG;             // [M,E] 16 MB (written last among GEMMs)
  // early split scratch aliased inside vreg (dead before vreg is written):
  short* sb = (short*)vreg;
  short* WqT_h = sb + 0 * MEG; short* WqT_l = sb + 1 * MEG;
  short* WkT_h = sb + 2 * MEG; short* WkT_l = sb + 3 * MEG;
  short* Wfq_h = sb + 4 * MEG; short* Wfq_l = sb + 5 * MEG;
  short* Wfk_h = sb + 6 * MEG; short* Wfk_l = sb + 7 * MEG;
  // persistent split buffers
  short* hs_h = (short*)(ws + 12 * MEG);  // 8 MB
  short* hs_l = hs_h + 4 * MEG;           // 8 MB (ends at ws+16M floats)
  short* Wv_h = (short*)(ws + 16 * MEG); short* Wv_l = Wv_h + MEG;
  short* WcQ_h = (short*)(ws + 17 * MEG); short* WcQ_l = WcQ_h + MEG;
  short* WcK_h = (short*)(ws + 18 * MEG); short* WcK_l = WcK_h + MEG;
  float* bcQ = ws + 19 * MEG;
  float* bcK = bcQ + 1024;
  // KV partials alias hs splits (dead after the big GEMM):
  float* KVp = (float*)hs_h;              // 32*16*4096 floats = 8 MB
  float* ksump = (float*)hs_l;            // 32*16*64 floats = 128 KB

  // 1) Fused prep: splits + transposes + bias combines.
  prep<<<4352, 256, 0, stream>>>(Wfq, Wfq_h, Wfq_l, Wfk, Wfk_h, Wfk_l,
                                 Wv, Wv_h, Wv_l, hs, hs_h, hs_l,
                                 Wq, WqT_h, WqT_l, Wk, WkT_h, WkT_l,
                                 bq, bfq, bcQ, bk, bfk, bcK);
  // 2) Combined weights Wc = Wf @ W, emitted pre-split. [1024,1024,K=1024] x2.
  GArgs sw0 = {Wfq_h, Wfq_l, WqT_h, WqT_l, nullptr, (void*)WcQ_h, (void*)WcQ_l};
  GArgs sw1 = {Wfk_h, Wfk_l, WkT_h, WkT_l, nullptr, (void*)WcK_h, (void*)WcK_l};
  gemm3s<64, 1><<<dim3(16, 8, 2), 256, 0, stream>>>(sw0, sw1, sw1, E, E);
  // 3) Fused big GEMM (z=3): q-logits, k-logits, v. [4096,1024,K=1024] each.
  GArgs bg0 = {hs_h, hs_l, WcQ_h, WcQ_l, bcQ, (void*)qf, nullptr};
  GArgs bg1 = {hs_h, hs_l, WcK_h, WcK_l, bcK, (void*)kf, nullptr};
  GArgs bg2 = {hs_h, hs_l, Wv_h, Wv_l, bv, (void*)vreg, nullptr};
  gemm3s<128, 0><<<dim3(32, 8, 3), 256, 0, stream>>>(bg0, bg1, bg2, E, E);
  // 4) Row softmax (q and k).
  softmax2<<<dim3(M, 2), 256, 0, stream>>>(qf, kf);
  // 5) KV partials (overwrites hs splits; no atomics/memset).
  kv_part<<<dim3(B * H, S / 128), 256, 0, stream>>>(kf, vreg, KVp, ksump);
  // 6) Output.
  out_v3<<<dim3(B * H, S / 256), 256, 0, stream>>>(qf, KVp, ksump, out);
}

// Round 7
// 268.212 us; speedup vs baseline: 1.2206x; 1.0962x over previous
//
#include <hip/hip_runtime.h>
#include <math.h>

constexpr int B = 2, S = 2048, E = 1024, H = 16, D = 64;
constexpr int M = B * S;  // 4096
constexpr int CH = 8;     // kv chunks per (b,h)

typedef __attribute__((ext_vector_type(8))) short short8;
typedef __attribute__((ext_vector_type(8))) _Float16 half8;
typedef __attribute__((ext_vector_type(4))) float f32x4;
#define MFMA_BF16 __builtin_amdgcn_mfma_f32_16x16x32_bf16
#define MFMA_F16 __builtin_amdgcn_mfma_f32_16x16x32_f16
// wait until at most N vector-memory ops outstanding; leave lgkm/exp unconstrained
#define WAITCNT_VM(N) __builtin_amdgcn_s_waitcnt(0xF70 | (N))

// Split fp32 into hi = bf16-truncate(x), lo = bf16-truncate(x - hi). Combined rel err ~2^-16.
__device__ __forceinline__ void split1(float f, short* h, short* l) {
  unsigned u = __float_as_uint(f);
  *h = (short)(u >> 16);
  float r = f - __uint_as_float(u & 0xFFFF0000u);
  *l = (short)(__float_as_uint(r) >> 16);
}
__device__ __forceinline__ short f2h(float f) {
  _Float16 h = (_Float16)f;
  short s;
  __builtin_memcpy(&s, &h, 2);
  return s;
}
__device__ __forceinline__ float h2f(short s) {
  _Float16 h;
  __builtin_memcpy(&h, &s, 2);
  return (float)h;
}

// Async global->LDS DMA, 16B per lane. LDS dest = wave-uniform base + lane*16.
__device__ __forceinline__ void gload16(const void* g, const void* l) {
  __builtin_amdgcn_global_load_lds(
      (const __attribute__((address_space(1))) unsigned*)g,
      (__attribute__((address_space(3))) unsigned*)l, 16, 0, 0);
}

struct SArgs {  // split-bf16 path
  const short* Ah; const short* Al;  // A [Mrows x K] bf16 hi/lo
  const short* Bh; const short* Bl;  // B [N x K] bf16 hi/lo
  const float* bias;                 // WEMIT=0
  float* C;                          // WEMIT=0: fp32 out
  short* Ch; short* Cl;              // WEMIT=1: split bf16 out
};
struct HArgs {  // fp16 path
  const short* A; const short* Bm;   // fp16 bits
  const float* bias;                 // WEMIT=0
  short* C;                          // fp16 out
  float* Zrow;                       // if set (WEMIT=0): store exp(val), += rowsum exp
};

// One dispatch, two precision modes (wave-uniform branch on blockIdx.z):
//   z==0: split-bf16 3-MFMA, single-buffered LDS (q path, ~2^-22 rel err)
//   z>=1: fp16 1-MFMA, double-buffered pipelined LDS (k/v paths)
// BM in {64,128}, BN=128, 256 threads = 4 waves (2x2), K%64==0.
// LDS: (BM/8+16)*1KB — identical for both modes (32 KB at BM=128).
template <int BM, int WEMIT>
__global__ __launch_bounds__(256, 2) void gemm_combo(SArgs s, HArgs ha, HArgs hb, int K, int N) {
  __shared__ short lds[(BM / 8 + 16) * 512];
  const int tid = threadIdx.x, wave = tid >> 6, lane = tid & 63;
  const int bm = blockIdx.x * BM, bn = blockIdx.y * 128;
  const int fr = lane & 15, fq = lane >> 4;
  const int wm = (wave & 1) * (BM / 2), wn = (wave >> 1) * 64;
  constexpr int MT = BM / 32;

  if (blockIdx.z == 0) {
    // ---------------- split-bf16 3-MFMA path ----------------
    constexpr int SA = BM / 16;
    constexpr int TOT = 2 * SA + 16;
    constexpr int PW = TOT / 4;
    const short* gb[PW];
#pragma unroll
    for (int j = 0; j < PW; ++j) {
      const int n = wave * PW + j;
      const short* src; int seg, rowbase;
      if (n < SA)              { src = s.Ah; seg = n;            rowbase = bm; }
      else if (n < 2 * SA)     { src = s.Al; seg = n - SA;       rowbase = bm; }
      else if (n < 2 * SA + 8) { src = s.Bh; seg = n - 2 * SA;   rowbase = bn; }
      else                     { src = s.Bl; seg = n - 2 * SA - 8; rowbase = bn; }
      const int r = seg * 16 + (lane >> 2);   // row within tile
      const int p = lane & 3;                 // LDS chunk slot this lane fills
      const int q = (p - ((r >> 1) & 3)) & 3; // k-chunk that belongs in slot p (swizzle)
      gb[j] = src + (size_t)(rowbase + r) * K + q * 8;
    }
    int aoh[MT], aol[MT], boh[4], bol[4];
#pragma unroll
    for (int mi = 0; mi < MT; ++mi) {
      const int r = wm + mi * 16 + fr;
      const int slot = (fq + ((r >> 1) & 3)) & 3;
      aoh[mi] = r * 32 + slot * 8;
      aol[mi] = BM * 32 + aoh[mi];
    }
#pragma unroll
    for (int ni = 0; ni < 4; ++ni) {
      const int r = wn + ni * 16 + fr;
      const int slot = (fq + ((r >> 1) & 3)) & 3;
      boh[ni] = 2 * BM * 32 + r * 32 + slot * 8;
      bol[ni] = boh[ni] + 4096;
    }
    f32x4 acc[MT][4] = {};
    const int ldsW = wave * PW * 512;
    for (int k0 = 0; k0 < K; k0 += 32) {
#pragma unroll
      for (int j = 0; j < PW; ++j) gload16(gb[j] + k0, &lds[ldsW + j * 512]);
      __syncthreads();  // compiler drains vmcnt(0) before s_barrier
      short8 ah[MT], al[MT], bh4[4], bl4[4];
#pragma unroll
      for (int mi = 0; mi < MT; ++mi) {
        ah[mi] = *(const short8*)&lds[aoh[mi]];
        al[mi] = *(const short8*)&lds[aol[mi]];
      }
#pragma unroll
      for (int ni = 0; ni < 4; ++ni) {
        bh4[ni] = *(const short8*)&lds[boh[ni]];
        bl4[ni] = *(const short8*)&lds[bol[ni]];
      }
#pragma unroll
      for (int mi = 0; mi < MT; ++mi)
#pragma unroll
        for (int ni = 0; ni < 4; ++ni) {
          acc[mi][ni] = MFMA_BF16(ah[mi], bh4[ni], acc[mi][ni], 0, 0, 0);
          acc[mi][ni] = MFMA_BF16(ah[mi], bl4[ni], acc[mi][ni], 0, 0, 0);
          acc[mi][ni] = MFMA_BF16(al[mi], bh4[ni], acc[mi][ni], 0, 0, 0);
        }
      __syncthreads();
    }
    // epilogue: C/D layout col=lane&15, row=(lane>>4)*4+reg
    if (WEMIT == 0) {
      float* C = s.C;
#pragma unroll
      for (int ni = 0; ni < 4; ++ni) {
        const int n = bn + wn + ni * 16 + fr;
        const float bv = s.bias[n];
#pragma unroll
        for (int mi = 0; mi < MT; ++mi) {
          const int m0 = bm + wm + mi * 16 + fq * 4;
#pragma unroll
          for (int r2 = 0; r2 < 4; ++r2)
            C[(size_t)(m0 + r2) * N + n] = acc[mi][ni][r2] + bv;
        }
      }
    } else {
      short* Chp = s.Ch; short* Clp = s.Cl;
#pragma unroll
      for (int ni = 0; ni < 4; ++ni) {
        const int n = bn + wn + ni * 16 + fr;
#pragma unroll
        for (int mi = 0; mi < MT; ++mi) {
          const int m0 = bm + wm + mi * 16 + fq * 4;
#pragma unroll
          for (int r2 = 0; r2 < 4; ++r2) {
            short hh, ll;
            split1(acc[mi][ni][r2], &hh, &ll);
            Chp[(size_t)(m0 + r2) * N + n] = hh;
            Clp[(size_t)(m0 + r2) * N + n] = ll;
          }
        }
      }
    }
    return;
  }

  // ---------------- fp16 1-MFMA path (pipelined) ----------------
  const HArgs h = (blockIdx.z == 1) ? ha : hb;
  constexpr int SAh = BM / 16;
  constexpr int TOTh = SAh + 8;
  constexpr int PWh = TOTh / 4;
  const short* gb[PWh];
#pragma unroll
  for (int j = 0; j < PWh; ++j) {
    const int n = wave * PWh + j;
    const short* src; int seg, rowbase;
    if (n < SAh) { src = h.A;  seg = n;       rowbase = bm; }
    else         { src = h.Bm; seg = n - SAh; rowbase = bn; }
    const int r = seg * 16 + (lane >> 2);
    const int p = lane & 3;
    const int q = (p - ((r >> 1) & 3)) & 3;
    gb[j] = src + (size_t)(rowbase + r) * K + q * 8;
  }
  int ao[MT], bo[4];
#pragma unroll
  for (int mi = 0; mi < MT; ++mi) {
    const int r = wm + mi * 16 + fr;
    ao[mi] = r * 32 + (((fq + ((r >> 1) & 3)) & 3)) * 8;
  }
#pragma unroll
  for (int ni = 0; ni < 4; ++ni) {
    const int r = wn + ni * 16 + fr;
    bo[ni] = BM * 32 + r * 32 + (((fq + ((r >> 1) & 3)) & 3)) * 8;
  }
  f32x4 acc[MT][4] = {};
  const int ldsW = wave * PWh * 512;
  auto stageAll = [&](int buf, int k0) {
#pragma unroll
    for (int j = 0; j < PWh; ++j)
      gload16(gb[j] + k0, &lds[buf * TOTh * 512 + ldsW + j * 512]);
  };
  stageAll(0, 0);
  stageAll(1, 32);
  int buf = 0;
  for (int k0 = 0; k0 < K; k0 += 32) {
    if (k0 + 32 < K) WAITCNT_VM(PWh); else WAITCNT_VM(0);
    __builtin_amdgcn_s_barrier();
    half8 ah[MT], bh4[4];
    const int bb = buf * TOTh * 512;
#pragma unroll
    for (int mi = 0; mi < MT; ++mi) ah[mi] = *(const half8*)&lds[bb + ao[mi]];
#pragma unroll
    for (int ni = 0; ni < 4; ++ni) bh4[ni] = *(const half8*)&lds[bb + bo[ni]];
#pragma unroll
    for (int mi = 0; mi < MT; ++mi)
#pragma unroll
      for (int ni = 0; ni < 4; ++ni)
        acc[mi][ni] = MFMA_F16(ah[mi], bh4[ni], acc[mi][ni], 0, 0, 0);
    __builtin_amdgcn_s_barrier();  // all waves done reading lds[buf]
    if (k0 + 64 < K) stageAll(buf, k0 + 64);
    buf ^= 1;
  }
  if (WEMIT == 0) {
    short* C = h.C;
    float bv4[4];
#pragma unroll
    for (int ni = 0; ni < 4; ++ni) bv4[ni] = h.bias[bn + wn + ni * 16 + fr];
#pragma unroll
    for (int mi = 0; mi < MT; ++mi)
#pragma unroll
      for (int r2 = 0; r2 < 4; ++r2) {
        const int m = bm + wm + mi * 16 + fq * 4 + r2;
        float vals[4];
#pragma unroll
        for (int ni = 0; ni < 4; ++ni) vals[ni] = acc[mi][ni][r2] + bv4[ni];
        if (h.Zrow) {  // k path: store exp(logit), accumulate row sums of exp
          float es = 0.f;
#pragma unroll
          for (int ni = 0; ni < 4; ++ni) { vals[ni] = __expf(vals[ni]); es += vals[ni]; }
#pragma unroll
          for (int off = 1; off < 16; off <<= 1) es += __shfl_xor(es, off, 16);
          if (fr == 0) atomicAdd(&h.Zrow[m], es);
        }
#pragma unroll
        for (int ni = 0; ni < 4; ++ni)
          C[(size_t)m * N + bn + wn + ni * 16 + fr] = f2h(vals[ni]);
      }
  } else {
    short* C = h.C;
#pragma unroll
    for (int ni = 0; ni < 4; ++ni) {
      const int n = bn + wn + ni * 16 + fr;
#pragma unroll
      for (int mi = 0; mi < MT; ++mi) {
        const int m0 = bm + wm + mi * 16 + fq * 4;
#pragma unroll
        for (int r2 = 0; r2 < 4; ++r2)
          C[(size_t)(m0 + r2) * N + n] = f2h(acc[mi][ni][r2]);
      }
    }
  }
}

// One fused prep dispatch (4352 blocks):
//   [0,1024)    hs -> bf16 hi/lo + fp16
//   [1024,1280) Wfq -> bf16 hi/lo     [1280,1536) Wfk -> fp16   [1536,1792) Wv -> fp16
//   [1792,2816) Wq transpose -> bf16 hi/lo
//   [2816,3840) Wk transpose -> fp16
//   [3840,4352) bias combine bc = Wf @ b + bf (fp32)
__global__ __launch_bounds__(256) void prep(
    const float* __restrict__ hs, short* hs_h, short* hs_l, short* hs_f,
    const float* __restrict__ Wfq, short* Wfq_h, short* Wfq_l,
    const float* __restrict__ Wfk, short* Wfk_f,
    const float* __restrict__ Wv, short* Wv_f,
    const float* __restrict__ Wq, short* WqT_h, short* WqT_l,
    const float* __restrict__ Wk, short* WkT_f,
    const float* __restrict__ bq, const float* __restrict__ bfq, float* bcQ,
    const float* __restrict__ bk, const float* __restrict__ bfk, float* bcK) {
  __shared__ float tb[32][33];
  const int blk = blockIdx.x, tid = threadIdx.x;
  if (blk < 1024) {
#pragma unroll
    for (int p = 0; p < 4; ++p) {
      const int i = blk * 1024 + p * 256 + tid;
      float4 v = ((const float4*)hs)[i];
      short4 hh, ll;
      split1(v.x, &hh.x, &ll.x); split1(v.y, &hh.y, &ll.y);
      split1(v.z, &hh.z, &ll.z); split1(v.w, &hh.w, &ll.w);
      ((short4*)hs_h)[i] = hh; ((short4*)hs_l)[i] = ll;
      ((short4*)hs_f)[i] = make_short4(f2h(v.x), f2h(v.y), f2h(v.z), f2h(v.w));
    }
  } else if (blk < 1280) {
    const int base = blk - 1024;
#pragma unroll
    for (int p = 0; p < 4; ++p) {
      const int i = base * 1024 + p * 256 + tid;
      float4 v = ((const float4*)Wfq)[i];
      short4 hh, ll;
      split1(v.x, &hh.x, &ll.x); split1(v.y, &hh.y, &ll.y);
      split1(v.z, &hh.z, &ll.z); split1(v.w, &hh.w, &ll.w);
      ((short4*)Wfq_h)[i] = hh; ((short4*)Wfq_l)[i] = ll;
    }
  } else if (blk < 1792) {
    const int base = blk - 1280;  // [0,512): first 256 = Wfk, next 256 = Wv
    const float* src = (base < 256) ? Wfk : Wv;
    short* dst = (base < 256) ? Wfk_f : Wv_f;
    const int bb = base & 255;
#pragma unroll
    for (int p = 0; p < 4; ++p) {
      const int i = bb * 1024 + p * 256 + tid;
      float4 v = ((const float4*)src)[i];
      ((short4*)dst)[i] = make_short4(f2h(v.x), f2h(v.y), f2h(v.z), f2h(v.w));
    }
  } else if (blk < 2816) {
    const int tt = blk - 1792;
    const int bx = (tt & 31) * 32, by = (tt >> 5) * 32;
    const int x = tid & 31, y0 = tid >> 5;
#pragma unroll
    for (int i = 0; i < 32; i += 8) tb[y0 + i][x] = Wq[(size_t)(by + y0 + i) * E + bx + x];
    __syncthreads();
#pragma unroll
    for (int i = 0; i < 32; i += 8) {
      short hh, ll;
      split1(tb[x][y0 + i], &hh, &ll);
      const size_t o = (size_t)(bx + y0 + i) * E + by + x;
      WqT_h[o] = hh; WqT_l[o] = ll;
    }
  } else if (blk < 3840) {
    const int tt = blk - 2816;
    const int bx = (tt & 31) * 32, by = (tt >> 5) * 32;
    const int x = tid & 31, y0 = tid >> 5;
#pragma unroll
    for (int i = 0; i < 32; i += 8) tb[y0 + i][x] = Wk[(size_t)(by + y0 + i) * E + bx + x];
    __syncthreads();
#pragma unroll
    for (int i = 0; i < 32; i += 8)
      WkT_f[(size_t)(bx + y0 + i) * E + by + x] = f2h(tb[x][y0 + i]);
  } else {
    const int t = blk - 3840;
    const float* Wf = (t < 256) ? Wfq : Wfk;
    const float* bin = (t < 256) ? bq : bk;
    const float* bf = (t < 256) ? bfq : bfk;
    float* o = (t < 256) ? bcQ : bcK;
    const int n = (t & 255) * 4 + (tid >> 6);
    const int lane = tid & 63;
    float sacc = 0.f;
    for (int j = lane; j < E; j += 64) sacc += Wf[(size_t)n * E + j] * bin[j];
#pragma unroll
    for (int off = 32; off; off >>= 1) sacc += __shfl_xor(sacc, off, 64);
    if (lane == 0) o[n] = sacc + bf[n];
  }
}

// KV partials from stored e = exp(k logit) (fp16): k = e * invZ applied inline.
// Block (bh, chunk of 256 t). KVp[(bh*CH+c)][64][64], ksump[(bh*CH+c)][64].
__global__ __launch_bounds__(256) void kv_part(const short* __restrict__ kh,
                                               const short* __restrict__ vh,
                                               const float* __restrict__ Zk,
                                               float* __restrict__ KVp,
                                               float* __restrict__ ksump) {
  const int bh = blockIdx.x;
  const int b = bh / H, h = bh % H;
  const int t0 = blockIdx.y * (S / CH);
  const short* kbase = kh + (size_t)b * S * E + (size_t)h * D;
  const short* vbase = vh + (size_t)b * S * E + (size_t)h * D;
  __shared__ float ks[16][D];
  __shared__ float vs[16][D];
  __shared__ float invZs[S / CH];
  const int tid = threadIdx.x;
  invZs[tid] = 1.0f / Zk[b * S + t0 + tid];  // FIX: batch offset b*S (was missing -> R5/R6 fail)
  const int a4 = tid & 15, b4 = tid >> 4;
  float acc[4][4] = {};
  float ksm[4] = {};
  for (int ts = 0; ts < S / CH; ts += 16) {
    __syncthreads();
#pragma unroll
    for (int i = 0; i < 4; ++i) {
      const int idx = tid + i * 256;
      const int tt = idx >> 6, d = idx & 63;
      const size_t roff = (size_t)(t0 + ts + tt) * E + d;
      ks[tt][d] = h2f(kbase[roff]) * invZs[ts + tt];
      vs[tt][d] = h2f(vbase[roff]);
    }
    __syncthreads();
#pragma unroll
    for (int tt = 0; tt < 16; ++tt) {
      float kk4[4], vv4[4];
#pragma unroll
      for (int i = 0; i < 4; ++i) kk4[i] = ks[tt][a4 * 4 + i];
#pragma unroll
      for (int j = 0; j < 4; ++j) vv4[j] = vs[tt][b4 * 4 + j];
#pragma unroll
      for (int i = 0; i < 4; ++i) {
        ksm[i] += kk4[i];
#pragma unroll
        for (int j = 0; j < 4; ++j) acc[i][j] = fmaf(kk4[i], vv4[j], acc[i][j]);
      }
    }
  }
  float* kvout = KVp + ((size_t)bh * CH + blockIdx.y) * 4096;
#pragma unroll
  for (int i = 0; i < 4; ++i)
#pragma unroll
    for (int j = 0; j < 4; ++j)
      kvout[(a4 * 4 + i) * 64 + b4 * 4 + j] = acc[i][j];
  if (b4 == 0) {
    float* kso = ksump + ((size_t)bh * CH + blockIdx.y) * 64;
#pragma unroll
    for (int i = 0; i < 4; ++i) kso[a4 * 4 + i] = ksm[i];
  }
}

// Output from RAW fp32 q logits: u = exp(l) (q softmax normalization cancels).
// Block (bh, 256-row chunk); reduces CH KV partials into LDS once.
__global__ __launch_bounds__(256) void out_v4(const float* __restrict__ qf,
                                              const float* __restrict__ KVp,
                                              const float* __restrict__ ksump,
                                              float* __restrict__ out) {
  const int bh = blockIdx.x;
  const int b = bh >> 4, h = bh & 15;
  __shared__ float KVs[64][65];
  __shared__ float kss[64];
  __shared__ float qs[4][64];
  const int tid = threadIdx.x;
  for (int i = tid; i < 4096; i += 256) {
    float s = 0.f;
#pragma unroll
    for (int c = 0; c < CH; ++c) s += KVp[((size_t)bh * CH + c) * 4096 + i];
    KVs[i >> 6][i & 63] = s;
  }
  if (tid < 64) {
    float s = 0.f;
#pragma unroll
    for (int c = 0; c < CH; ++c) s += ksump[((size_t)bh * CH + c) * 64 + tid];
    kss[tid] = s;
  }
  __syncthreads();
  const int wave = tid >> 6, lane = tid & 63;
  const int r0 = blockIdx.y * 256;
  for (int rr = r0 + wave; rr < r0 + 256; rr += 4) {
    const size_t rowoff = ((size_t)b * S + rr) * E + h * 64;
    const float u = __expf(qf[rowoff + lane]);
    float dn = u * kss[lane];
#pragma unroll
    for (int off = 32; off; off >>= 1) dn += __shfl_xor(dn, off, 64);
    qs[wave][lane] = u;
    float num = 0.f;
#pragma unroll 16
    for (int d = 0; d < 64; ++d) num = fmaf(qs[wave][d], KVs[d][lane], num);
    out[rowoff + lane] = num / dn;
  }
}

extern "C" void kernel_launch(void* const* d_in, const int* in_sizes, int n_in,
                              void* d_out, int out_size, void* d_ws, size_t ws_size,
                              hipStream_t stream) {
  const float* hs = (const float*)d_in[0];
  const float* Wq = (const float*)d_in[1];
  const float* bq = (const float*)d_in[2];
  const float* Wk = (const float*)d_in[3];
  const float* bk = (const float*)d_in[4];
  const float* Wv = (const float*)d_in[5];
  const float* bv = (const float*)d_in[6];
  const float* Wfq = (const float*)d_in[7];
  const float* bfq = (const float*)d_in[8];
  const float* Wfk = (const float*)d_in[9];
  const float* bfk = (const float*)d_in[10];
  float* out = (float*)d_out;

  const size_t MEG = 1024 * 1024;
  float* ws = (float*)d_ws;
  float* qf = ws;                                       // [M,E] fp32 (16 MB)
  short* kh = (short*)(ws + 4 * MEG);                   // [M,E] fp16 e=exp(k logit) (8 MB)
  short* vh = (short*)(ws + 6 * MEG);                   // [M,E] fp16 v (8 MB)
  short* hs_h = (short*)(ws + 8 * MEG);                 // bf16 hi (8 MB)
  short* hs_l = (short*)(ws + 10 * MEG);                // bf16 lo (8 MB)
  short* hs_f = (short*)(ws + 12 * MEG);                // fp16 (8 MB)
  short* Wfq_h = (short*)(ws + 14 * MEG);
  short* Wfq_l = (short*)(ws + 14 * MEG + 512 * 1024);
  short* WqT_h = (short*)(ws + 15 * MEG);
  short* WqT_l = (short*)(ws + 15 * MEG + 512 * 1024);
  short* Wfk_f = (short*)(ws + 16 * MEG);
  short* WkT_f = (short*)(ws + 16 * MEG + 512 * 1024);
  short* Wv_f = (short*)(ws + 17 * MEG);
  short* WcQ_h = (short*)(ws + 17 * MEG + 512 * 1024);
  short* WcQ_l = (short*)(ws + 18 * MEG);
  short* WcK_f = (short*)(ws + 18 * MEG + 512 * 1024);
  float* bcQ = ws + 19 * MEG;
  float* bcK = bcQ + 1024;
  float* Zk = bcK + 1024;                               // [M]
  // KV partials alias hs_h/hs_l (dead after big GEMM):
  float* KVp = (float*)hs_h;                            // 32*CH*4096 floats (4 MB)
  float* ksump = KVp + 32 * CH * 4096;

  // 0) Zero the Zk accumulator.
  hipMemsetAsync(Zk, 0, M * sizeof(float), stream);
  // 1) Fused prep: conversions + transposes + bias combines.
  prep<<<4352, 256, 0, stream>>>(hs, hs_h, hs_l, hs_f,
                                 Wfq, Wfq_h, Wfq_l, Wfk, Wfk_f, Wv, Wv_f,
                                 Wq, WqT_h, WqT_l, Wk, WkT_f,
                                 bq, bfq, bcQ, bk, bfk, bcK);
  // 2) Combined weights: z=0 split WcQ = Wfq@Wq (bf16-split out), z=1 fp16 WcK = Wfk@Wk.
  SArgs sw = {Wfq_h, Wfq_l, WqT_h, WqT_l, nullptr, nullptr, WcQ_h, WcQ_l};
  HArgs hw = {Wfk_f, WkT_f, nullptr, WcK_f, nullptr};
  gemm_combo<64, 1><<<dim3(16, 8, 2), 256, 0, stream>>>(sw, hw, hw, E, E);
  // 3) Big GEMM: z=0 split q logits (fp32); z=1 fp16 k -> exp stored fp16 + Zk; z=2 fp16 v.
  SArgs sb = {hs_h, hs_l, WcQ_h, WcQ_l, bcQ, qf, nullptr, nullptr};
  HArgs hk = {hs_f, WcK_f, bcK, kh, Zk};
  HArgs hv = {hs_f, Wv_f, bv, vh, nullptr};
  gemm_combo<128, 0><<<dim3(32, 8, 3), 256, 0, stream>>>(sb, hk, hv, E, E);
  // 4) KV partials (1/Zk applied inline, correct batch offset).
  kv_part<<<dim3(B * H, CH), 256, 0, stream>>>(kh, vh, Zk, KVp, ksump);
  // 5) Output (exp applied inline; q normalization cancels).
  out_v4<<<dim3(B * H, S / 256), 256, 0, stream>>>(qf, KVp, ksump, out);
}